// Round 3
// baseline (337.506 us; speedup 1.0000x reference)
//
#include <hip/hip_runtime.h>
#include <hip/hip_bf16.h>

// Problem constants (reference: B=32, S=2048, D=1024, F=512, E=8, GROUP=32 -> 1 group)
#define SS 2048
#define BB 32
#define DD 1024
#define FF 512
#define EE 8

typedef __attribute__((ext_vector_type(8))) short short8;
typedef __attribute__((ext_vector_type(8))) unsigned short ushort8v;
typedef __attribute__((ext_vector_type(4))) unsigned short ushort4v;
typedef __attribute__((ext_vector_type(4))) float f32x4;

__device__ inline unsigned short f2bf(float f) {
  union { float f; unsigned u; } v; v.f = f;
  return (unsigned short)((v.u + 0x7FFFu + ((v.u >> 16) & 1u)) >> 16);
}
__device__ inline float bf2f(unsigned short h) {
  union { unsigned u; float f; } v; v.u = ((unsigned)h) << 16;
  return v.f;
}

// ---------------- ctrl (D,E) f32 -> ctrlT (E,D) f32
__global__ __launch_bounds__(256) void ctrl_transpose(
    const float* __restrict__ ctrl, float* __restrict__ ctrlT) {
  int i = blockIdx.x * 256 + threadIdx.x;  // 0..8191
  int e = i >> 10, d = i & 1023;
  ctrlT[i] = ctrl[(size_t)d * EE + e];
}

// ---------------- transpose + fp32->bf16 cast: in (E,K,N) f32 -> out (E,N,K) bf16
__global__ __launch_bounds__(256) void transpose_bf16(
    const float* __restrict__ in, unsigned short* __restrict__ out, int K, int N) {
  __shared__ float tile[32][33];
  int e = blockIdx.z;
  const float* inp = in + (size_t)e * K * N;
  unsigned short* outp = out + (size_t)e * K * N;
  int k0 = blockIdx.x * 32, n0 = blockIdx.y * 32;
  int tx = threadIdx.x;   // 0..31
  int ty = threadIdx.y;   // 0..7
#pragma unroll
  for (int i = 0; i < 4; i++) {
    int k = ty + i * 8;
    tile[k][tx] = inp[(size_t)(k0 + k) * N + n0 + tx];
  }
  __syncthreads();
#pragma unroll
  for (int i = 0; i < 4; i++) {
    int n = ty + i * 8;
    outp[(size_t)(n0 + n) * K + k0 + tx] = f2bf(tile[tx][n]);
  }
}

// ---------------- logits only: lg[s,k,e] = x[k,s,:] . ctrlT[e,:]
// block per s, 512 threads = 8 waves; wave owns 4 tokens; lane owns 16 d's.
// Single barrier (ctrl staging); everything else is barrier-free -> waves overlap.
__global__ __launch_bounds__(512) void ctrl_logits(
    const float* __restrict__ x,       // (B,S,D) f32
    const float* __restrict__ ctrlT,   // (E,D) f32
    float* __restrict__ lg) {          // (S,B,E) f32
  int s = blockIdx.x;
  int t = threadIdx.x, lane = t & 63, w = t >> 6;
  __shared__ __align__(16) float cs[EE * DD];   // 32 KiB
  for (int i = t; i < EE * DD / 4; i += 512)
    *(float4*)&cs[i * 4] = *(const float4*)&ctrlT[i * 4];
  __syncthreads();

  float acc[4][8] = {};
#pragma unroll
  for (int i = 0; i < 4; i++) {
    int dbase = lane * 4 + i * 256;
    float4 c4[8];
#pragma unroll
    for (int e = 0; e < 8; e++) c4[e] = *(const float4*)&cs[e * DD + dbase];
#pragma unroll
    for (int j = 0; j < 4; j++) {
      int k = w * 4 + j;
      float4 xv = *(const float4*)&x[((size_t)k * SS + s) * DD + dbase];
#pragma unroll
      for (int e = 0; e < 8; e++)
        acc[j][e] += xv.x * c4[e].x + xv.y * c4[e].y + xv.z * c4[e].z + xv.w * c4[e].w;
    }
  }
  // butterfly reduce each of 32 values over the 64 lanes
#pragma unroll
  for (int off = 1; off < 64; off <<= 1)
#pragma unroll
    for (int j = 0; j < 4; j++)
#pragma unroll
      for (int e = 0; e < 8; e++)
        acc[j][e] += __shfl_xor(acc[j][e], off, 64);
  if (lane == 0) {
#pragma unroll
    for (int j = 0; j < 4; j++) {
      int k = w * 4 + j;
      float4 lo = {acc[j][0], acc[j][1], acc[j][2], acc[j][3]};
      float4 hi = {acc[j][4], acc[j][5], acc[j][6], acc[j][7]};
      float* p = &lg[((size_t)s * BB + k) * EE];
      *(float4*)p = lo;
      *(float4*)(p + 4) = hi;
    }
  }
}

// ---------------- softmax over tokens + merge (fp32 x re-read, L3-hot)
// block per s, 256 threads, ~1 KiB LDS -> high occupancy
__global__ __launch_bounds__(256) void softmax_merge(
    const float* __restrict__ x,          // (B,S,D) f32
    const float* __restrict__ lg,         // (S,B,E) f32
    unsigned short* __restrict__ merged,  // (S,E,D) bf16
    float* __restrict__ mw) {             // (S,B,E) f32
  int s = blockIdx.x;
  int t = threadIdx.x;
  __shared__ __align__(16) float wl[BB][EE];
  wl[t >> 3][t & 7] = lg[(size_t)s * BB * EE + t];
  __syncthreads();
  if (t < 32) {
    float lgv[8], mx[8], p[8], sm[8];
#pragma unroll
    for (int e = 0; e < 8; e++) { lgv[e] = wl[t][e]; mx[e] = lgv[e]; }
#pragma unroll
    for (int off = 1; off < 32; off <<= 1)
#pragma unroll
      for (int e = 0; e < 8; e++)
        mx[e] = fmaxf(mx[e], __shfl_xor(mx[e], off, 64));
#pragma unroll
    for (int e = 0; e < 8; e++) { p[e] = __expf(lgv[e] - mx[e]); sm[e] = p[e]; }
#pragma unroll
    for (int off = 1; off < 32; off <<= 1)
#pragma unroll
      for (int e = 0; e < 8; e++)
        sm[e] += __shfl_xor(sm[e], off, 64);
    float wv[8];
#pragma unroll
    for (int e = 0; e < 8; e++) { wv[e] = p[e] / sm[e]; wl[t][e] = wv[e]; }
    float4 mv0 = {wv[0], wv[1], wv[2], wv[3]};
    float4 mv1 = {wv[4], wv[5], wv[6], wv[7]};
    float* mwp = &mw[((size_t)s * BB + t) * EE];
    *(float4*)mwp = mv0;
    *(float4*)(mwp + 4) = mv1;
  }
  __syncthreads();

  // merge: thread owns d0 = 4t..4t+3; acc[e][c] over 32 tokens (fp32 inputs)
  int d0 = t * 4;
  float a[8][4] = {};
#pragma unroll 4
  for (int k = 0; k < 32; k++) {
    float4 xv = *(const float4*)&x[((size_t)k * SS + s) * DD + d0];
    float4 wA = *(const float4*)&wl[k][0];
    float4 wB = *(const float4*)&wl[k][4];
    a[0][0] += wA.x * xv.x; a[0][1] += wA.x * xv.y; a[0][2] += wA.x * xv.z; a[0][3] += wA.x * xv.w;
    a[1][0] += wA.y * xv.x; a[1][1] += wA.y * xv.y; a[1][2] += wA.y * xv.z; a[1][3] += wA.y * xv.w;
    a[2][0] += wA.z * xv.x; a[2][1] += wA.z * xv.y; a[2][2] += wA.z * xv.z; a[2][3] += wA.z * xv.w;
    a[3][0] += wA.w * xv.x; a[3][1] += wA.w * xv.y; a[3][2] += wA.w * xv.z; a[3][3] += wA.w * xv.w;
    a[4][0] += wB.x * xv.x; a[4][1] += wB.x * xv.y; a[4][2] += wB.x * xv.z; a[4][3] += wB.x * xv.w;
    a[5][0] += wB.y * xv.x; a[5][1] += wB.y * xv.y; a[5][2] += wB.y * xv.z; a[5][3] += wB.y * xv.w;
    a[6][0] += wB.z * xv.x; a[6][1] += wB.z * xv.y; a[6][2] += wB.z * xv.z; a[6][3] += wB.z * xv.w;
    a[7][0] += wB.w * xv.x; a[7][1] += wB.w * xv.y; a[7][2] += wB.w * xv.z; a[7][3] += wB.w * xv.w;
  }
#pragma unroll
  for (int e = 0; e < 8; e++) {
    ushort4v pv;
    pv[0] = f2bf(a[e][0]); pv[1] = f2bf(a[e][1]);
    pv[2] = f2bf(a[e][2]); pv[3] = f2bf(a[e][3]);
    *(ushort4v*)&merged[((size_t)s * EE + e) * DD + d0] = pv;
  }
}

// ---------------- bf16 MFMA GEMM with global_load_lds staging (m97 pattern)
// Linear LDS dest + XOR-swizzled global source + swizzled ds_read (rule #21).
// A: (S, E, K) bf16 ; Bt: (E, N, K) bf16 ; C: (S, E, N) bf16
// grid: (S/128, N/128, E), 256 threads = 4 waves (2x2), wave tile 64x64, 16x16x32 frags
template <int RELU>
__global__ __launch_bounds__(256) void gemm_bt(
    const unsigned short* __restrict__ A, const unsigned short* __restrict__ Bt,
    unsigned short* __restrict__ C, int K, int N) {
  int e = blockIdx.z;
  int m0 = blockIdx.x * 128;
  int n0 = blockIdx.y * 128;
  const int lda = EE * K;
  const unsigned short* Ae = A + (size_t)e * K;
  const unsigned short* Be = Bt + (size_t)e * N * K;

  __shared__ __align__(16) unsigned short As[128 * 32];  // linear, 8 KiB
  __shared__ __align__(16) unsigned short Bs[128 * 32];

  int t = threadIdx.x;
  int lane = t & 63, w = t >> 6;
  int wm = w >> 1, wn = w & 1;
  int lr = lane & 15;                    // fragment row within 16
  int kh = lane >> 4;                    // k-quarter 0..3
  int khs = kh ^ ((lr >> 1) & 3);        // swizzled read slot (XOR involution)

  f32x4 acc[4][4] = {};

  for (int kt = 0; kt < K; kt += 32) {
    // stage 128x32 A and B tiles; chunk c -> LDS linear (wave-uniform base + lane*16),
    // global source slot XOR-swizzled so swizzled reads see correct data.
#pragma unroll
    for (int i = 0; i < 2; i++) {
      int c = t + i * 256;               // 0..511
      int r = c >> 2;
      int subg = (c & 3) ^ ((r >> 1) & 3);
      __builtin_amdgcn_global_load_lds(
          (const __attribute__((address_space(1))) void*)(Ae + (size_t)(m0 + r) * lda + kt + subg * 8),
          (__attribute__((address_space(3))) void*)(&As[c * 8]), 16, 0, 0);
      __builtin_amdgcn_global_load_lds(
          (const __attribute__((address_space(1))) void*)(Be + (size_t)(n0 + r) * K + kt + subg * 8),
          (__attribute__((address_space(3))) void*)(&Bs[c * 8]), 16, 0, 0);
    }
    __syncthreads();

    short8 af[4], bfr[4];
#pragma unroll
    for (int mi = 0; mi < 4; mi++)
      af[mi] = *(const short8*)&As[(wm * 64 + mi * 16 + lr) * 32 + khs * 8];
#pragma unroll
    for (int ni = 0; ni < 4; ni++)
      bfr[ni] = *(const short8*)&Bs[(wn * 64 + ni * 16 + lr) * 32 + khs * 8];
#pragma unroll
    for (int mi = 0; mi < 4; mi++)
#pragma unroll
      for (int ni = 0; ni < 4; ni++)
        acc[mi][ni] = __builtin_amdgcn_mfma_f32_16x16x32_bf16(af[mi], bfr[ni], acc[mi][ni], 0, 0, 0);
    __syncthreads();
  }

  // epilogue: C/D layout col=lane&15, row=(lane>>4)*4+reg  [verified m89]
  int rb = (lane >> 4) * 4;
  int cb = lane & 15;
#pragma unroll
  for (int mi = 0; mi < 4; mi++)
#pragma unroll
    for (int ni = 0; ni < 4; ni++)
#pragma unroll
      for (int r = 0; r < 4; r++) {
        float v = acc[mi][ni][r];
        if (RELU) v = fmaxf(v, 0.f);
        int m = m0 + wm * 64 + mi * 16 + rb + r;
        int n = n0 + wn * 64 + ni * 16 + cb;
        C[(size_t)m * (EE * N) + (size_t)e * N + n] = f2bf(v);
      }
}

// ---------------- emit: out[b,s,d] = sum_e mw[s,b,e] * eo[s,e,d]
// 256 threads; thread owns d = 4t..4t+3; float4 stores
__global__ __launch_bounds__(256) void emit_out(
    const unsigned short* __restrict__ eo,  // (S,E,D) bf16
    const float* __restrict__ mw,           // (S,B,E) f32
    float* __restrict__ out) {              // (B,S,D) f32
  int s = blockIdx.x;
  int t = threadIdx.x;
  __shared__ float wsm[BB][EE];
  wsm[t >> 3][t & 7] = mw[(size_t)s * BB * EE + t];
  __syncthreads();
  int d0 = t * 4;
  float ev[EE][4];
#pragma unroll
  for (int e2 = 0; e2 < 8; e2++) {
    ushort4v v = *(const ushort4v*)&eo[((size_t)s * EE + e2) * DD + d0];
    ev[e2][0] = bf2f(v[0]); ev[e2][1] = bf2f(v[1]);
    ev[e2][2] = bf2f(v[2]); ev[e2][3] = bf2f(v[3]);
  }
  for (int b = 0; b < BB; b++) {
    float o0 = 0.f, o1 = 0.f, o2 = 0.f, o3 = 0.f;
#pragma unroll
    for (int e2 = 0; e2 < 8; e2++) {
      float we = wsm[b][e2];
      o0 += we * ev[e2][0]; o1 += we * ev[e2][1];
      o2 += we * ev[e2][2]; o3 += we * ev[e2][3];
    }
    float4 ov = {o0, o1, o2, o3};
    *(float4*)&out[((size_t)b * SS + s) * DD + d0] = ov;
  }
}

extern "C" void kernel_launch(void* const* d_in, const int* in_sizes, int n_in,
                              void* d_out, int out_size, void* d_ws, size_t ws_size,
                              hipStream_t stream) {
  const float* x = (const float*)d_in[0];        // (32, 2048, 1024)
  const float* lin1 = (const float*)d_in[1];     // (8, 1024, 512)
  const float* lin2 = (const float*)d_in[2];     // (8, 512, 1024)
  const float* ctrl = (const float*)d_in[3];     // (1024, 8)
  float* out = (float*)d_out;

  char* ws = (char*)d_ws;
  size_t off = 0;
  unsigned short* lin1t = (unsigned short*)(ws + off); off += (size_t)EE * DD * FF * 2;  // 8 MiB
  unsigned short* lin2t = (unsigned short*)(ws + off); off += (size_t)EE * FF * DD * 2;  // 8 MiB
  unsigned short* merged = (unsigned short*)(ws + off); off += (size_t)SS * EE * DD * 2; // 32 MiB
  unsigned short* hbuf = (unsigned short*)(ws + off); off += (size_t)SS * EE * FF * 2;   // 16 MiB
  unsigned short* eo = (unsigned short*)(ws + off); off += (size_t)SS * EE * DD * 2;     // 32 MiB
  float* mw = (float*)(ws + off); off += (size_t)SS * BB * EE * 4;                       // 2 MiB
  float* lg = (float*)(ws + off); off += (size_t)SS * BB * EE * 4;                       // 2 MiB
  float* ctrlT = (float*)(ws + off); off += (size_t)EE * DD * 4;                         // 32 KiB

  ctrl_transpose<<<32, 256, 0, stream>>>(ctrl, ctrlT);

  dim3 tb(32, 8);
  // lin1 (E, K=D, N=F) -> lin1t (E, F, D)
  transpose_bf16<<<dim3(DD / 32, FF / 32, EE), tb, 0, stream>>>(lin1, lin1t, DD, FF);
  // lin2 (E, K=F, N=D) -> lin2t (E, D, F)
  transpose_bf16<<<dim3(FF / 32, DD / 32, EE), tb, 0, stream>>>(lin2, lin2t, FF, DD);

  ctrl_logits<<<SS, 512, 0, stream>>>(x, ctrlT, lg);
  softmax_merge<<<SS, 256, 0, stream>>>(x, lg, merged, mw);

  // h = relu(merged @ lin1): M=S per expert, K=D, N=F
  gemm_bt<1><<<dim3(SS / 128, FF / 128, EE), 256, 0, stream>>>(merged, lin1t, hbuf, DD, FF);
  // eo = h @ lin2: K=F, N=D
  gemm_bt<0><<<dim3(SS / 128, DD / 128, EE), 256, 0, stream>>>(hbuf, lin2t, eo, FF, DD);

  emit_out<<<SS, 256, 0, stream>>>(eo, mw, out);
}

// Round 4
// 333.235 us; speedup vs baseline: 1.0128x; 1.0128x over previous
//
#include <hip/hip_runtime.h>
#include <hip/hip_bf16.h>

// Problem constants (reference: B=32, S=2048, D=1024, F=512, E=8, GROUP=32 -> 1 group)
#define SS 2048
#define BB 32
#define DD 1024
#define FF 512
#define EE 8

typedef __attribute__((ext_vector_type(8))) short short8;
typedef __attribute__((ext_vector_type(8))) unsigned short ushort8v;
typedef __attribute__((ext_vector_type(4))) unsigned short ushort4v;
typedef __attribute__((ext_vector_type(4))) float f32x4;

__device__ inline unsigned short f2bf(float f) {
  union { float f; unsigned u; } v; v.f = f;
  return (unsigned short)((v.u + 0x7FFFu + ((v.u >> 16) & 1u)) >> 16);
}
__device__ inline float bf2f(unsigned short h) {
  union { unsigned u; float f; } v; v.u = ((unsigned)h) << 16;
  return v.f;
}

// ---------------- transpose + fp32->bf16 cast: in (E,K,N) f32 -> out (E,N,K) bf16
__global__ __launch_bounds__(256) void transpose_bf16(
    const float* __restrict__ in, unsigned short* __restrict__ out, int K, int N) {
  __shared__ float tile[32][33];
  int e = blockIdx.z;
  const float* inp = in + (size_t)e * K * N;
  unsigned short* outp = out + (size_t)e * K * N;
  int k0 = blockIdx.x * 32, n0 = blockIdx.y * 32;
  int tx = threadIdx.x;   // 0..31
  int ty = threadIdx.y;   // 0..7
#pragma unroll
  for (int i = 0; i < 4; i++) {
    int k = ty + i * 8;
    tile[k][tx] = inp[(size_t)(k0 + k) * N + n0 + tx];
  }
  __syncthreads();
#pragma unroll
  for (int i = 0; i < 4; i++) {
    int n = ty + i * 8;
    outp[(size_t)(n0 + n) * K + k0 + tx] = f2bf(tile[tx][n]);
  }
}

// ---------------- fused: logits + softmax + merge. One block per s, 512 threads.
// LDS = ctrl copy (32 KiB) + weights (1 KiB) -> 2 blocks/CU co-resident.
// Phase A: wave w owns tokens 4w..4w+3, lane owns 16 d's; x streamed from HBM
//          (coalesced float4), slab lands in L2/L3.
// Phase B: wave-parallel softmax over the 32 tokens (lanes 0..31).
// Phase C: merge re-reads x from global (L2/L3-hot: this block just streamed it).
__global__ __launch_bounds__(512) void ctrl_merge_f(
    const float* __restrict__ x,          // (B,S,D) f32
    const float* __restrict__ ctrl,       // (D,E) f32
    unsigned short* __restrict__ merged,  // (S,E,D) bf16
    float* __restrict__ mw) {             // (S,B,E) f32
  int s = blockIdx.x;
  int t = threadIdx.x, lane = t & 63, w = t >> 6;

  __shared__ __align__(16) float cs[EE * DD];   // 32 KiB, ctrl as [e][d]
  __shared__ __align__(16) float wl[BB][EE];

  // stage ctrl (D,E) -> cs[e*DD+d]; coalesced global read, scattered LDS write
  for (int i = t; i < DD * EE; i += 512) {
    int d = i >> 3, e2 = i & 7;
    cs[e2 * DD + d] = ctrl[i];
  }
  __syncthreads();

  // ---- phase A: logits
  float acc[4][8] = {};
#pragma unroll
  for (int i = 0; i < 4; i++) {
    int dbase = lane * 4 + i * 256;
    float4 c4[8];
#pragma unroll
    for (int e = 0; e < 8; e++) c4[e] = *(const float4*)&cs[e * DD + dbase];
#pragma unroll
    for (int j = 0; j < 4; j++) {
      int k = w * 4 + j;
      float4 xv = *(const float4*)&x[((size_t)k * SS + s) * DD + dbase];
#pragma unroll
      for (int e = 0; e < 8; e++)
        acc[j][e] += xv.x * c4[e].x + xv.y * c4[e].y + xv.z * c4[e].z + xv.w * c4[e].w;
    }
  }
#pragma unroll
  for (int off = 1; off < 64; off <<= 1)
#pragma unroll
    for (int j = 0; j < 4; j++)
#pragma unroll
      for (int e = 0; e < 8; e++)
        acc[j][e] += __shfl_xor(acc[j][e], off, 64);
  if (lane == 0) {
#pragma unroll
    for (int j = 0; j < 4; j++)
#pragma unroll
      for (int e = 0; e < 8; e++)
        wl[w * 4 + j][e] = acc[j][e];
  }
  __syncthreads();

  // ---- phase B: softmax over tokens per expert column (lanes 0..31 of wave 0)
  if (t < 32) {
    float lgv[8], mx[8], p[8], sm[8];
#pragma unroll
    for (int e = 0; e < 8; e++) { lgv[e] = wl[t][e]; mx[e] = lgv[e]; }
#pragma unroll
    for (int off = 1; off < 32; off <<= 1)
#pragma unroll
      for (int e = 0; e < 8; e++)
        mx[e] = fmaxf(mx[e], __shfl_xor(mx[e], off, 64));
#pragma unroll
    for (int e = 0; e < 8; e++) { p[e] = __expf(lgv[e] - mx[e]); sm[e] = p[e]; }
#pragma unroll
    for (int off = 1; off < 32; off <<= 1)
#pragma unroll
      for (int e = 0; e < 8; e++)
        sm[e] += __shfl_xor(sm[e], off, 64);
    float wv[8];
#pragma unroll
    for (int e = 0; e < 8; e++) { wv[e] = p[e] / sm[e]; wl[t][e] = wv[e]; }
    float4 mv0 = {wv[0], wv[1], wv[2], wv[3]};
    float4 mv1 = {wv[4], wv[5], wv[6], wv[7]};
    float* mwp = &mw[((size_t)s * BB + t) * EE];
    *(float4*)mwp = mv0;
    *(float4*)(mwp + 4) = mv1;
  }
  __syncthreads();

  // ---- phase C: merged[e][d] = sum_k w[k][e]*x[k][d]; thread owns d0 = 2t (float2)
  int d0 = t * 2;
  float a0[8] = {}, a1[8] = {};
#pragma unroll 4
  for (int k = 0; k < 32; k++) {
    float2 xv = *(const float2*)&x[((size_t)k * SS + s) * DD + d0];
    float4 wA = *(const float4*)&wl[k][0];
    float4 wB = *(const float4*)&wl[k][4];
    a0[0] += wA.x * xv.x; a1[0] += wA.x * xv.y;
    a0[1] += wA.y * xv.x; a1[1] += wA.y * xv.y;
    a0[2] += wA.z * xv.x; a1[2] += wA.z * xv.y;
    a0[3] += wA.w * xv.x; a1[3] += wA.w * xv.y;
    a0[4] += wB.x * xv.x; a1[4] += wB.x * xv.y;
    a0[5] += wB.y * xv.x; a1[5] += wB.y * xv.y;
    a0[6] += wB.z * xv.x; a1[6] += wB.z * xv.y;
    a0[7] += wB.w * xv.x; a1[7] += wB.w * xv.y;
  }
#pragma unroll
  for (int e = 0; e < 8; e++) {
    unsigned pm = (unsigned)f2bf(a0[e]) | ((unsigned)f2bf(a1[e]) << 16);
    *(unsigned*)&merged[((size_t)s * EE + e) * DD + d0] = pm;
  }
}

// ---------------- bf16 MFMA GEMM with global_load_lds staging (m97 pattern)
// Linear LDS dest + XOR-swizzled global source + swizzled ds_read (rule #21).
// A: (S, E, K) bf16 ; Bt: (E, N, K) bf16 ; C: (S, E, N) bf16
// grid: (S/128, N/128, E), 256 threads = 4 waves (2x2), wave tile 64x64, 16x16x32 frags
template <int RELU>
__global__ __launch_bounds__(256) void gemm_bt(
    const unsigned short* __restrict__ A, const unsigned short* __restrict__ Bt,
    unsigned short* __restrict__ C, int K, int N) {
  int e = blockIdx.z;
  int m0 = blockIdx.x * 128;
  int n0 = blockIdx.y * 128;
  const int lda = EE * K;
  const unsigned short* Ae = A + (size_t)e * K;
  const unsigned short* Be = Bt + (size_t)e * N * K;

  __shared__ __align__(16) unsigned short As[128 * 32];  // linear, 8 KiB
  __shared__ __align__(16) unsigned short Bs[128 * 32];

  int t = threadIdx.x;
  int lane = t & 63, w = t >> 6;
  int wm = w >> 1, wn = w & 1;
  int lr = lane & 15;                    // fragment row within 16
  int kh = lane >> 4;                    // k-quarter 0..3
  int khs = kh ^ ((lr >> 1) & 3);        // swizzled read slot (XOR involution)

  f32x4 acc[4][4] = {};

  for (int kt = 0; kt < K; kt += 32) {
#pragma unroll
    for (int i = 0; i < 2; i++) {
      int c = t + i * 256;               // 0..511
      int r = c >> 2;
      int subg = (c & 3) ^ ((r >> 1) & 3);
      __builtin_amdgcn_global_load_lds(
          (const __attribute__((address_space(1))) void*)(Ae + (size_t)(m0 + r) * lda + kt + subg * 8),
          (__attribute__((address_space(3))) void*)(&As[c * 8]), 16, 0, 0);
      __builtin_amdgcn_global_load_lds(
          (const __attribute__((address_space(1))) void*)(Be + (size_t)(n0 + r) * K + kt + subg * 8),
          (__attribute__((address_space(3))) void*)(&Bs[c * 8]), 16, 0, 0);
    }
    __syncthreads();

    short8 af[4], bfr[4];
#pragma unroll
    for (int mi = 0; mi < 4; mi++)
      af[mi] = *(const short8*)&As[(wm * 64 + mi * 16 + lr) * 32 + khs * 8];
#pragma unroll
    for (int ni = 0; ni < 4; ni++)
      bfr[ni] = *(const short8*)&Bs[(wn * 64 + ni * 16 + lr) * 32 + khs * 8];
#pragma unroll
    for (int mi = 0; mi < 4; mi++)
#pragma unroll
      for (int ni = 0; ni < 4; ni++)
        acc[mi][ni] = __builtin_amdgcn_mfma_f32_16x16x32_bf16(af[mi], bfr[ni], acc[mi][ni], 0, 0, 0);
    __syncthreads();
  }

  // epilogue: C/D layout col=lane&15, row=(lane>>4)*4+reg  [verified m89]
  int rb = (lane >> 4) * 4;
  int cb = lane & 15;
#pragma unroll
  for (int mi = 0; mi < 4; mi++)
#pragma unroll
    for (int ni = 0; ni < 4; ni++)
#pragma unroll
      for (int r = 0; r < 4; r++) {
        float v = acc[mi][ni][r];
        if (RELU) v = fmaxf(v, 0.f);
        int m = m0 + wm * 64 + mi * 16 + rb + r;
        int n = n0 + wn * 64 + ni * 16 + cb;
        C[(size_t)m * (EE * N) + (size_t)e * N + n] = f2bf(v);
      }
}

// ---------------- emit: out[b,s,d] = sum_e mw[s,b,e] * eo[s,e,d]
// 256 threads; thread owns d = 4t..4t+3; float4 stores
__global__ __launch_bounds__(256) void emit_out(
    const unsigned short* __restrict__ eo,  // (S,E,D) bf16
    const float* __restrict__ mw,           // (S,B,E) f32
    float* __restrict__ out) {              // (B,S,D) f32
  int s = blockIdx.x;
  int t = threadIdx.x;
  __shared__ float wsm[BB][EE];
  wsm[t >> 3][t & 7] = mw[(size_t)s * BB * EE + t];
  __syncthreads();
  int d0 = t * 4;
  float ev[EE][4];
#pragma unroll
  for (int e2 = 0; e2 < 8; e2++) {
    ushort4v v = *(const ushort4v*)&eo[((size_t)s * EE + e2) * DD + d0];
    ev[e2][0] = bf2f(v[0]); ev[e2][1] = bf2f(v[1]);
    ev[e2][2] = bf2f(v[2]); ev[e2][3] = bf2f(v[3]);
  }
  for (int b = 0; b < BB; b++) {
    float o0 = 0.f, o1 = 0.f, o2 = 0.f, o3 = 0.f;
#pragma unroll
    for (int e2 = 0; e2 < 8; e2++) {
      float we = wsm[b][e2];
      o0 += we * ev[e2][0]; o1 += we * ev[e2][1];
      o2 += we * ev[e2][2]; o3 += we * ev[e2][3];
    }
    float4 ov = {o0, o1, o2, o3};
    *(float4*)&out[((size_t)b * SS + s) * DD + d0] = ov;
  }
}

extern "C" void kernel_launch(void* const* d_in, const int* in_sizes, int n_in,
                              void* d_out, int out_size, void* d_ws, size_t ws_size,
                              hipStream_t stream) {
  const float* x = (const float*)d_in[0];        // (32, 2048, 1024)
  const float* lin1 = (const float*)d_in[1];     // (8, 1024, 512)
  const float* lin2 = (const float*)d_in[2];     // (8, 512, 1024)
  const float* ctrl = (const float*)d_in[3];     // (1024, 8)
  float* out = (float*)d_out;

  char* ws = (char*)d_ws;
  size_t off = 0;
  unsigned short* lin1t = (unsigned short*)(ws + off); off += (size_t)EE * DD * FF * 2;  // 8 MiB
  unsigned short* lin2t = (unsigned short*)(ws + off); off += (size_t)EE * FF * DD * 2;  // 8 MiB
  unsigned short* merged = (unsigned short*)(ws + off); off += (size_t)SS * EE * DD * 2; // 32 MiB
  unsigned short* hbuf = (unsigned short*)(ws + off); off += (size_t)SS * EE * FF * 2;   // 16 MiB
  unsigned short* eo = (unsigned short*)(ws + off); off += (size_t)SS * EE * DD * 2;     // 32 MiB
  float* mw = (float*)(ws + off); off += (size_t)SS * BB * EE * 4;                       // 2 MiB

  dim3 tb(32, 8);
  // lin1 (E, K=D, N=F) -> lin1t (E, F, D)
  transpose_bf16<<<dim3(DD / 32, FF / 32, EE), tb, 0, stream>>>(lin1, lin1t, DD, FF);
  // lin2 (E, K=F, N=D) -> lin2t (E, D, F)
  transpose_bf16<<<dim3(FF / 32, DD / 32, EE), tb, 0, stream>>>(lin2, lin2t, FF, DD);

  ctrl_merge_f<<<SS, 512, 0, stream>>>(x, ctrl, merged, mw);

  // h = relu(merged @ lin1): M=S per expert, K=D, N=F
  gemm_bt<1><<<dim3(SS / 128, FF / 128, EE), 256, 0, stream>>>(merged, lin1t, hbuf, DD, FF);
  // eo = h @ lin2: K=F, N=D
  gemm_bt<0><<<dim3(SS / 128, DD / 128, EE), 256, 0, stream>>>(hbuf, lin2t, eo, FF, DD);

  emit_out<<<SS, 256, 0, stream>>>(eo, mw, out);
}